// Round 8
// baseline (676.613 us; speedup 1.0000x reference)
//
#include <hip/hip_runtime.h>
#include <cstdint>
#include <cstddef>

// ---------------------------------------------------------------------------
// CrossAttention fused pipeline for MI355X (gfx950)
//  B=4, LQ=LK=2048, D=512, H=8, DH=64, SCALE=0.125, TOPK=205
//  kernel 1 (proj):  q/k/v projections (MFMA f16), +bias, qk-L2norm (q scaled
//                    by 0.125), tanh(v);  writes Q[bh][l][e], K[bh][k][e],
//                    V^T[bh][e][k] as fp16.
//  kernel 2 (attn):  per WG = 32 query rows of one (b,h), 16 waves, keys
//                    split 128/wave.  S^T in REGISTERS (sp[32] packed f16x2).
//                    Cross-wave ctx reduce via ds_add_f32 atomics into an
//                    8.7 KB LDS buffer (prev 139 KB cred array capped the CU
//                    at ONE 1024-thread WG -> barriers drained all waves;
//                    now ~17 KB LDS -> 2 WGs/CU, 32 waves, stall overlap).
//  kernel 3 (out):   ctx[8192x512] @ Wo^T + bo -> f32 d_out
// ---------------------------------------------------------------------------

typedef _Float16 f16;
typedef __attribute__((ext_vector_type(2))) _Float16 f16x2;
typedef __attribute__((ext_vector_type(4))) _Float16 f16x4;
typedef __attribute__((ext_vector_type(8))) _Float16 f16x8;
typedef __attribute__((ext_vector_type(4))) float f32x4;

#define MFMA16(a, b, c) __builtin_amdgcn_mfma_f32_16x16x32_f16((a), (b), (c), 0, 0, 0)
#define MFMA16K16(a, b, c) __builtin_amdgcn_mfma_f32_16x16x16f16((a), (b), (c), 0, 0, 0)

static __device__ __forceinline__ f16x8 ldg8(const f16* p) {
  return __builtin_bit_cast(f16x8, *(const uint4*)(p));
}
static __device__ __forceinline__ f16x4 ldg4(const f16* p) {
  return __builtin_bit_cast(f16x4, *(const uint2*)(p));
}
static __device__ __forceinline__ unsigned pkrtz(float a, float b) {
  return __builtin_bit_cast(unsigned, __builtin_amdgcn_cvt_pkrtz(a, b));
}

// ---------------------------------------------------------------------------
// Kernel 1: projections
// grid (64, 12): x = 128-token tile, y = 128-outcol tile (0-3 q, 4-7 k, 8-11 v)
// ---------------------------------------------------------------------------
__global__ __launch_bounds__(256) void proj_kernel(
    const float* __restrict__ Xq, const float* __restrict__ Xk, const float* __restrict__ Xv,
    const float* __restrict__ Wq, const float* __restrict__ Wk, const float* __restrict__ Wv,
    const float* __restrict__ Bq, const float* __restrict__ Bk, const float* __restrict__ Bv,
    const unsigned char* __restrict__ mask,
    f16* __restrict__ Qf, f16* __restrict__ Kf, f16* __restrict__ VTf)
{
  __shared__ __align__(16) f16 As[128 * 32];
  __shared__ __align__(16) f16 Bs[128 * 32];
  __shared__ float biasS[128];

  const int tid = threadIdx.x;
  const int m0 = blockIdx.x * 128;
  const int n0 = blockIdx.y * 128;
  const int which = n0 >> 9;  // 0=q 1=k 2=v
  const float* X = (which == 0) ? Xq : (which == 1) ? Xk : Xv;
  const float* W = (which == 0) ? Wq : (which == 1) ? Wk : Wv;
  const float* Bi = (which == 0) ? Bq : (which == 1) ? Bk : Bv;
  const int nIn = n0 & 511;

  if (tid < 128) biasS[tid] = Bi[nIn + tid];

  const int w = tid >> 6, lane = tid & 63;
  const int l15 = lane & 15, g = lane >> 4;
  const int mh = w >> 1, nh = w & 1;

  f32x4 acc[4][4];
#pragma unroll
  for (int i = 0; i < 4; ++i)
#pragma unroll
    for (int j = 0; j < 4; ++j) acc[i][j] = (f32x4){0.f, 0.f, 0.f, 0.f};

  const int srow = tid >> 1;
  const int d0 = (tid & 1) * 16;

  for (int k0 = 0; k0 < 512; k0 += 32) {
    {
      const float4* xp4 = (const float4*)(X + (size_t)(m0 + srow) * 512 + k0 + d0);
      float4 x0 = xp4[0], x1 = xp4[1], x2 = xp4[2], x3 = xp4[3];
      f16x8 h0 = {(f16)x0.x, (f16)x0.y, (f16)x0.z, (f16)x0.w,
                  (f16)x1.x, (f16)x1.y, (f16)x1.z, (f16)x1.w};
      f16x8 h1 = {(f16)x2.x, (f16)x2.y, (f16)x2.z, (f16)x2.w,
                  (f16)x3.x, (f16)x3.y, (f16)x3.z, (f16)x3.w};
      const int base = srow * 32, sw = (srow & 3) << 3;
      *(uint4*)(As + base + ((d0 + 0) ^ sw)) = __builtin_bit_cast(uint4, h0);
      *(uint4*)(As + base + ((d0 + 8) ^ sw)) = __builtin_bit_cast(uint4, h1);
      const float4* wp4 = (const float4*)(W + (size_t)(nIn + srow) * 512 + k0 + d0);
      float4 w0 = wp4[0], w1 = wp4[1], w2 = wp4[2], w3 = wp4[3];
      f16x8 g0 = {(f16)w0.x, (f16)w0.y, (f16)w0.z, (f16)w0.w,
                  (f16)w1.x, (f16)w1.y, (f16)w1.z, (f16)w1.w};
      f16x8 g1 = {(f16)w2.x, (f16)w2.y, (f16)w2.z, (f16)w2.w,
                  (f16)w3.x, (f16)w3.y, (f16)w3.z, (f16)w3.w};
      *(uint4*)(Bs + base + ((d0 + 0) ^ sw)) = __builtin_bit_cast(uint4, g0);
      *(uint4*)(Bs + base + ((d0 + 8) ^ sw)) = __builtin_bit_cast(uint4, g1);
    }
    __syncthreads();
    f16x8 af[4], bf[4];
#pragma unroll
    for (int mt = 0; mt < 4; ++mt) {
      int row = mh * 64 + mt * 16 + l15;
      af[mt] = __builtin_bit_cast(f16x8, *(const uint4*)(As + row * 32 + ((8 * g) ^ ((row & 3) << 3))));
    }
#pragma unroll
    for (int nt = 0; nt < 4; ++nt) {
      int row = nh * 64 + nt * 16 + l15;
      bf[nt] = __builtin_bit_cast(f16x8, *(const uint4*)(Bs + row * 32 + ((8 * g) ^ ((row & 3) << 3))));
    }
#pragma unroll
    for (int mt = 0; mt < 4; ++mt)
#pragma unroll
      for (int nt = 0; nt < 4; ++nt)
        acc[mt][nt] = MFMA16(af[mt], bf[nt], acc[mt][nt]);
    __syncthreads();
  }

#pragma unroll
  for (int mt = 0; mt < 4; ++mt) {
#pragma unroll
    for (int r = 0; r < 4; ++r) {
      float val[4];
#pragma unroll
      for (int nt = 0; nt < 4; ++nt)
        val[nt] = acc[mt][nt][r] + biasS[nh * 64 + nt * 16 + l15];
      const int rowG = m0 + mh * 64 + mt * 16 + 4 * g + r;  // = b*2048 + tok
      if (which < 2) {
        float ss = 0.f;
#pragma unroll
        for (int nt = 0; nt < 4; ++nt) ss += val[nt] * val[nt];
#pragma unroll
        for (int off = 1; off < 16; off <<= 1) ss += __shfl_xor(ss, off);
        float inv = rsqrtf(fmaxf(ss, 1e-24f));
        if (which == 0) inv *= 0.125f;  // fold SCALE/ATTN_TEMP into q
        bool kill = (which == 1) && (mask[rowG] != 0);
#pragma unroll
        for (int nt = 0; nt < 4; ++nt) val[nt] = kill ? 0.f : val[nt] * inv;
      } else {
#pragma unroll
        for (int nt = 0; nt < 4; ++nt) {
          float x = fminf(fmaxf(val[nt], -15.f), 15.f);
          float t = exp2f(x * 2.88539008f);  // e^(2x)
          val[nt] = (t - 1.f) / (t + 1.f);   // tanh
        }
      }
      const int bb = rowG >> 11, tok = rowG & 2047;
#pragma unroll
      for (int nt = 0; nt < 4; ++nt) {
        const int cc = nIn + nh * 64 + nt * 16 + l15;
        const int hh = cc >> 6, ee = cc & 63;
        const size_t bhh = (size_t)bb * 8 + hh;
        if (which == 0)      Qf[(bhh * 2048 + tok) * 64 + ee] = (f16)val[nt];
        else if (which == 1) Kf[(bhh * 2048 + tok) * 64 + ee] = (f16)val[nt];
        else                 VTf[(bhh * 64 + ee) * 2048 + tok] = (f16)val[nt];
      }
    }
  }
}

// ---------------------------------------------------------------------------
// Kernel 2: fused attention, TQ=32, 16 waves / 128 keys each.
// grid 2048 (XCD-chunked), block 1024, ~17 KB LDS -> 2 WGs/CU
// ---------------------------------------------------------------------------
__global__ __launch_bounds__(1024, 4) void attn_kernel(
    const f16* __restrict__ Qf, const f16* __restrict__ Kf,
    const f16* __restrict__ VTf, f16* __restrict__ ctx)
{
  __shared__ float cred[32][68];        // 8,704 B, ds_add_f32 accumulation
  __shared__ unsigned cnt[2][16][32];   // 4,096 B, 2-buffer cycle
  __shared__ float mxA[16][32];         // 2,048 B
  __shared__ float zzA[16][32];         // 2,048 B

  const int tid = threadIdx.x;
  const int w = tid >> 6, lane = tid & 63;
  const int l15 = lane & 15, g = lane >> 4;

  // zero the atomic ctx accumulator (visibility via the stats barriers below)
  {
    float* cz = &cred[0][0];
    for (int i = tid; i < 32 * 68; i += 1024) cz[i] = 0.f;
  }

  const int bid = blockIdx.x;
  const int wg = (bid & 7) * 256 + (bid >> 3);   // XCD-chunked (2048 % 8 == 0)
  const int bh = wg >> 6;                        // 0..31 (4 bh per XCD)
  const int q0 = (wg & 63) * 32;
  const int b = bh >> 3, h = bh & 7;

  const f16* Qb = Qf + ((size_t)bh * 2048 + q0) * 64;
  const f16* Kb = Kf + (size_t)bh * 2048 * 64;
  const f16* VTb = VTf + (size_t)bh * 64 * 2048;

  // Q as B-operand for two q-groups: col = l15 (+16*qg), k(e) = ec*32 + 8g + j
  f16x8 aq[2][2];
#pragma unroll
  for (int qg = 0; qg < 2; ++qg)
#pragma unroll
    for (int ec = 0; ec < 2; ++ec)
      aq[qg][ec] = ldg8(Qb + (qg * 16 + l15) * 64 + ec * 32 + 8 * g);

  // ---- P1: S^T into registers; K fragments shared by both q-groups --------
  // lane (g,l15): sp[qg*16+2s+p] packs S[key=128w+16s+4g+2p(+1)][q=q0+16qg+l15]
  uint32_t sp[32];
  float m0 = -1e30f, m1 = -1e30f;
#pragma unroll
  for (int s = 0; s < 8; ++s) {
    const f16* kp = Kb + ((size_t)(w * 128 + s * 16 + l15)) * 64 + 8 * g;
    f16x8 ak0 = ldg8(kp);
    f16x8 ak1 = ldg8(kp + 32);
    f32x4 a0 = {0.f, 0.f, 0.f, 0.f}, a1 = {0.f, 0.f, 0.f, 0.f};
    a0 = MFMA16(ak0, aq[0][0], a0);
    a0 = MFMA16(ak1, aq[0][1], a0);
    a1 = MFMA16(ak0, aq[1][0], a1);
    a1 = MFMA16(ak1, aq[1][1], a1);
    m0 = fmaxf(m0, fmaxf(fmaxf(a0[0], a0[1]), fmaxf(a0[2], a0[3])));
    m1 = fmaxf(m1, fmaxf(fmaxf(a1[0], a1[1]), fmaxf(a1[2], a1[3])));
    sp[2 * s]          = pkrtz(a0[0], a0[1]);
    sp[2 * s + 1]      = pkrtz(a0[2], a0[3]);
    sp[16 + 2 * s]     = pkrtz(a1[0], a1[1]);
    sp[16 + 2 * s + 1] = pkrtz(a1[2], a1[3]);
  }

  // ---- per-row max partials (reduce over g within wave, stash in LDS) -----
  m0 = fmaxf(m0, __shfl_xor(m0, 16)); m0 = fmaxf(m0, __shfl_xor(m0, 32));
  m1 = fmaxf(m1, __shfl_xor(m1, 16)); m1 = fmaxf(m1, __shfl_xor(m1, 32));
  if (lane < 16) { mxA[w][l15] = m0; mxA[w][16 + l15] = m1; }

  // ---- exact-ish top-205 threshold: 6 count passes, both rows per lane ----
  float tau0 = 0.0200f, lo0 = -0.30f, hi0 = 0.30f, bt0 = tau0;
  float tau1 = 0.0200f, lo1 = -0.30f, hi1 = 0.30f, bt1 = tau1;
  int bd0 = 1 << 30, bd1 = 1 << 30;
  for (int p = 0; p < 6; ++p) {
    const f16 th0 = (f16)tau0, th1 = (f16)tau1;
    f16x2 t20; t20.x = th0; t20.y = th0;
    f16x2 t21; t21.x = th1; t21.y = th1;
    unsigned cc0 = 0, cc1 = 0;
#pragma unroll
    for (int i = 0; i < 16; ++i) {
      f16x2 d = t20 - __builtin_bit_cast(f16x2, sp[i]);   // sign iff v > tau
      cc0 += (__builtin_bit_cast(unsigned, d) >> 15) & 0x10001u;
    }
#pragma unroll
    for (int i = 16; i < 32; ++i) {
      f16x2 d = t21 - __builtin_bit_cast(f16x2, sp[i]);
      cc1 += (__builtin_bit_cast(unsigned, d) >> 15) & 0x10001u;
    }
    int c0 = (int)((cc0 & 0xffffu) + (cc0 >> 16));
    int c1 = (int)((cc1 & 0xffffu) + (cc1 >> 16));
    c0 += __shfl_xor(c0, 16); c0 += __shfl_xor(c0, 32);
    c1 += __shfl_xor(c1, 16); c1 += __shfl_xor(c1, 32);
    if (lane < 16) cnt[p & 1][w][l15] = (unsigned)c0 | ((unsigned)c1 << 16);
    __syncthreads();
    unsigned ct0 = 0, ct1 = 0;
#pragma unroll
    for (int i = 0; i < 16; ++i) {
      unsigned pk = cnt[p & 1][i][l15];
      ct0 += pk & 0xffffu;
      ct1 += pk >> 16;
    }
    {
      int d = (int)ct0 - 205, ad = d < 0 ? -d : d;
      if (ad < bd0) { bd0 = ad; bt0 = tau0; }
      if ((int)ct0 >= 205) lo0 = tau0; else hi0 = tau0;
      float nt = tau0 + (float)d * (1.0f / 23000.0f);
      if (!(nt > lo0 && nt < hi0)) nt = 0.5f * (lo0 + hi0);
      tau0 = nt;
    }
    {
      int d = (int)ct1 - 205, ad = d < 0 ? -d : d;
      if (ad < bd1) { bd1 = ad; bt1 = tau1; }
      if ((int)ct1 >= 205) lo1 = tau1; else hi1 = tau1;
      float nt = tau1 + (float)d * (1.0f / 23000.0f);
      if (!(nt > lo1 && nt < hi1)) nt = 0.5f * (lo1 + hi1);
      tau1 = nt;
    }
  }
  const float tf0 = (float)((f16)bt0);  // same comparisons as count pass
  const float tf1 = (float)((f16)bt1);

  // ---- row max across waves, single exp pass (Z + masked-e in place) ------
  float mm0 = mxA[0][l15], mm1 = mxA[0][16 + l15];
#pragma unroll
  for (int i = 1; i < 16; ++i) {
    mm0 = fmaxf(mm0, mxA[i][l15]);
    mm1 = fmaxf(mm1, mxA[i][16 + l15]);
  }
  const float L2E = 1.44269504f;
  const float mL0 = mm0 * L2E, mL1 = mm1 * L2E;
  float z0 = 0.f, z1 = 0.f;
#pragma unroll
  for (int i = 0; i < 16; ++i) {
    f16x2 v2 = __builtin_bit_cast(f16x2, sp[i]);
    float v0 = (float)v2.x, v1 = (float)v2.y;
    float e0 = __builtin_amdgcn_exp2f(__builtin_fmaf(v0, L2E, -mL0));
    float e1 = __builtin_amdgcn_exp2f(__builtin_fmaf(v1, L2E, -mL0));
    z0 += e0 + e1;
    sp[i] = pkrtz((v0 > tf0) ? e0 : 0.f, (v1 > tf0) ? e1 : 0.f);
  }
#pragma unroll
  for (int i = 16; i < 32; ++i) {
    f16x2 v2 = __builtin_bit_cast(f16x2, sp[i]);
    float v0 = (float)v2.x, v1 = (float)v2.y;
    float e0 = __builtin_amdgcn_exp2f(__builtin_fmaf(v0, L2E, -mL1));
    float e1 = __builtin_amdgcn_exp2f(__builtin_fmaf(v1, L2E, -mL1));
    z1 += e0 + e1;
    sp[i] = pkrtz((v0 > tf1) ? e0 : 0.f, (v1 > tf1) ? e1 : 0.f);
  }
  z0 += __shfl_xor(z0, 16); z0 += __shfl_xor(z0, 32);
  z1 += __shfl_xor(z1, 16); z1 += __shfl_xor(z1, 32);
  if (lane < 16) { zzA[w][l15] = z0; zzA[w][16 + l15] = z1; }
  __syncthreads();
  float Z0 = 0.f, Z1 = 0.f;
#pragma unroll
  for (int i = 0; i < 16; ++i) { Z0 += zzA[i][l15]; Z1 += zzA[i][16 + l15]; }

  // ---- finalize weights: w = 0.99*e/Z + eps (selected), 0 otherwise -------
  const float s0 = 0.99f / Z0, s1 = 0.99f / Z1;
  const float epsw = 0.01f / 2048.0f;
#pragma unroll
  for (int i = 0; i < 16; ++i) {
    f16x2 e2 = __builtin_bit_cast(f16x2, sp[i]);
    float e0 = (float)e2.x, e1 = (float)e2.y;
    sp[i] = pkrtz((e0 != 0.f) ? __builtin_fmaf(e0, s0, epsw) : 0.f,
                  (e1 != 0.f) ? __builtin_fmaf(e1, s0, epsw) : 0.f);
  }
#pragma unroll
  for (int i = 16; i < 32; ++i) {
    f16x2 e2 = __builtin_bit_cast(f16x2, sp[i]);
    float e0 = (float)e2.x, e1 = (float)e2.y;
    sp[i] = pkrtz((e0 != 0.f) ? __builtin_fmaf(e0, s1, epsw) : 0.f,
                  (e1 != 0.f) ? __builtin_fmaf(e1, s1, epsw) : 0.f);
  }

  // ---- P3: partial ctx^T over this wave's 128 keys; ds_add_f32 reduce -----
#pragma unroll
  for (int et = 0; et < 4; ++et) {
    const f16* vp = VTb + ((size_t)(et * 16 + l15)) * 2048 + w * 128 + 4 * g;
    f32x4 a0 = {0.f, 0.f, 0.f, 0.f}, a1 = {0.f, 0.f, 0.f, 0.f};
#pragma unroll
    for (int s = 0; s < 8; ++s) {
      f16x4 av = ldg4(vp + s * 16);
      uint2 p0; p0.x = sp[2 * s];      p0.y = sp[2 * s + 1];
      uint2 p1; p1.x = sp[16 + 2 * s]; p1.y = sp[16 + 2 * s + 1];
      a0 = MFMA16K16(av, __builtin_bit_cast(f16x4, p0), a0);
      a1 = MFMA16K16(av, __builtin_bit_cast(f16x4, p1), a1);
    }
#pragma unroll
    for (int r = 0; r < 4; ++r) {
      atomicAdd(&cred[l15][et * 16 + 4 * g + r], a0[r]);
      atomicAdd(&cred[16 + l15][et * 16 + 4 * g + r], a1[r]);
    }
  }
  __syncthreads();

  // ---- store ctx ----------------------------------------------------------
#pragma unroll
  for (int c = 0; c < 2; ++c) {
    const int cell = tid + c * 1024;      // 0..2047
    const int q = cell >> 6, e = cell & 63;
    ctx[((size_t)b * 2048 + q0 + q) * 512 + h * 64 + e] = (f16)cred[q][e];
  }
}

// ---------------------------------------------------------------------------
// Kernel 3: out = ctx @ Wo^T + bo.  grid (64, 4), block 256
// ---------------------------------------------------------------------------
__global__ __launch_bounds__(256) void out_kernel(
    const f16* __restrict__ CT, const float* __restrict__ Wo,
    const float* __restrict__ Bo, float* __restrict__ out)
{
  __shared__ __align__(16) f16 As[128 * 32];
  __shared__ __align__(16) f16 Bs[128 * 32];
  __shared__ float biasS[128];

  const int tid = threadIdx.x;
  const int m0 = blockIdx.x * 128;
  const int n0 = blockIdx.y * 128;
  if (tid < 128) biasS[tid] = Bo[n0 + tid];

  const int w = tid >> 6, lane = tid & 63;
  const int l15 = lane & 15, g = lane >> 4;
  const int mh = w >> 1, nh = w & 1;

  f32x4 acc[4][4];
#pragma unroll
  for (int i = 0; i < 4; ++i)
#pragma unroll
    for (int j = 0; j < 4; ++j) acc[i][j] = (f32x4){0.f, 0.f, 0.f, 0.f};

  const int srow = tid >> 1;
  const int d0 = (tid & 1) * 16;

  for (int k0 = 0; k0 < 512; k0 += 32) {
    {
      const uint4* ap = (const uint4*)(CT + (size_t)(m0 + srow) * 512 + k0 + d0);
      uint4 u0 = ap[0], u1 = ap[1];
      const int base = srow * 32, sw = (srow & 3) << 3;
      *(uint4*)(As + base + ((d0 + 0) ^ sw)) = u0;
      *(uint4*)(As + base + ((d0 + 8) ^ sw)) = u1;
      const float4* wp4 = (const float4*)(Wo + (size_t)(n0 + srow) * 512 + k0 + d0);
      float4 w0 = wp4[0], w1 = wp4[1], w2 = wp4[2], w3 = wp4[3];
      f16x8 g0 = {(f16)w0.x, (f16)w0.y, (f16)w0.z, (f16)w0.w,
                  (f16)w1.x, (f16)w1.y, (f16)w1.z, (f16)w1.w};
      f16x8 g1 = {(f16)w2.x, (f16)w2.y, (f16)w2.z, (f16)w2.w,
                  (f16)w3.x, (f16)w3.y, (f16)w3.z, (f16)w3.w};
      *(uint4*)(Bs + base + ((d0 + 0) ^ sw)) = __builtin_bit_cast(uint4, g0);
      *(uint4*)(Bs + base + ((d0 + 8) ^ sw)) = __builtin_bit_cast(uint4, g1);
    }
    __syncthreads();
    f16x8 af[4], bf[4];
#pragma unroll
    for (int mt = 0; mt < 4; ++mt) {
      int row = mh * 64 + mt * 16 + l15;
      af[mt] = __builtin_bit_cast(f16x8, *(const uint4*)(As + row * 32 + ((8 * g) ^ ((row & 3) << 3))));
    }
#pragma unroll
    for (int nt = 0; nt < 4; ++nt) {
      int row = nh * 64 + nt * 16 + l15;
      bf[nt] = __builtin_bit_cast(f16x8, *(const uint4*)(Bs + row * 32 + ((8 * g) ^ ((row & 3) << 3))));
    }
#pragma unroll
    for (int mt = 0; mt < 4; ++mt)
#pragma unroll
      for (int nt = 0; nt < 4; ++nt)
        acc[mt][nt] = MFMA16(af[mt], bf[nt], acc[mt][nt]);
    __syncthreads();
  }

#pragma unroll
  for (int mt = 0; mt < 4; ++mt) {
#pragma unroll
    for (int r = 0; r < 4; ++r) {
      const int rowG = m0 + mh * 64 + mt * 16 + 4 * g + r;
#pragma unroll
      for (int nt = 0; nt < 4; ++nt) {
        const int cc = nh * 64 + nt * 16 + l15;
        out[(size_t)rowG * 512 + n0 + cc] = acc[mt][nt][r] + biasS[cc];
      }
    }
  }
}

// ---------------------------------------------------------------------------
extern "C" void kernel_launch(void* const* d_in, const int* in_sizes, int n_in,
                              void* d_out, int out_size, void* d_ws, size_t ws_size,
                              hipStream_t stream)
{
  const float* q_in = (const float*)d_in[0];
  const float* k_in = (const float*)d_in[1];
  const float* v_in = (const float*)d_in[2];
  const float* Wq = (const float*)d_in[3];
  const float* bq = (const float*)d_in[4];
  const float* Wk = (const float*)d_in[5];
  const float* bk = (const float*)d_in[6];
  const float* Wv = (const float*)d_in[7];
  const float* bv = (const float*)d_in[8];
  const float* Wo = (const float*)d_in[9];
  const float* bo = (const float*)d_in[10];
  const unsigned char* mask = (const unsigned char*)d_in[11];

  // workspace: Q,K,VT,ctx fp16, 8 MB each = 32 MB total
  f16* Qf = (f16*)d_ws;
  f16* Kf = Qf + 4194304;
  f16* VTf = Kf + 4194304;
  f16* ctx = VTf + 4194304;

  proj_kernel<<<dim3(64, 12), 256, 0, stream>>>(q_in, k_in, v_in, Wq, Wk, Wv,
                                                bq, bk, bv, mask, Qf, Kf, VTf);
  attn_kernel<<<2048, 1024, 0, stream>>>(Qf, Kf, VTf, ctx);
  out_kernel<<<dim3(64, 4), 256, 0, stream>>>(ctx, Wo, bo, (float*)d_out);
}

// Round 9
// 360.767 us; speedup vs baseline: 1.8755x; 1.8755x over previous
//
#include <hip/hip_runtime.h>
#include <cstdint>
#include <cstddef>

// ---------------------------------------------------------------------------
// CrossAttention fused pipeline for MI355X (gfx950)
//  B=4, LQ=LK=2048, D=512, H=8, DH=64, SCALE=0.125, TOPK=205
//  kernel 1 (proj):  q/k/v projections (MFMA f16), +bias, qk-L2norm (q scaled
//                    by 0.125), tanh(v).  Writes Q/K/V in MFMA-FRAGMENT ORDER
//                    (base + lane*16B) so attn loads are fully coalesced:
//                      Q[bh][qt][qg][ec][lane][8]   (1KB/instr)
//                      K[bh][kblk][ec][lane][8]     (1KB/instr)
//                      V[bh][kblk][et][lane][4]     (512B/instr)
//                    (old row-major layouts scattered each wave-load over 16
//                    cache lines -> ~13K L2 transactions per WG, the real
//                    bottleneck of the 310 us attn kernel)
//  kernel 2 (attn):  per WG = 32 query rows of one (b,h), 16 waves, keys
//                    split 128/wave.  S^T in REGISTERS (sp[32] packed f16x2).
//                    Row stats (max / 6x topk-count / Z) via LDS + barriers.
//                    PV via mfma_16x16x16; cred f32 staging reduce (the LDS
//                    atomicAdd variant regressed 310->532 us: CAS serialization,
//                    and small LDS did NOT raise occupancy).
//  kernel 3 (out):   ctx[8192x512] @ Wo^T + bo -> f32 d_out
// ---------------------------------------------------------------------------

typedef _Float16 f16;
typedef __attribute__((ext_vector_type(2))) _Float16 f16x2;
typedef __attribute__((ext_vector_type(4))) _Float16 f16x4;
typedef __attribute__((ext_vector_type(8))) _Float16 f16x8;
typedef __attribute__((ext_vector_type(4))) float f32x4;

#define MFMA16(a, b, c) __builtin_amdgcn_mfma_f32_16x16x32_f16((a), (b), (c), 0, 0, 0)
#define MFMA16K16(a, b, c) __builtin_amdgcn_mfma_f32_16x16x16f16((a), (b), (c), 0, 0, 0)

static __device__ __forceinline__ f16x8 ldg8(const f16* p) {
  return __builtin_bit_cast(f16x8, *(const uint4*)(p));
}
static __device__ __forceinline__ f16x4 ldg4(const f16* p) {
  return __builtin_bit_cast(f16x4, *(const uint2*)(p));
}
static __device__ __forceinline__ unsigned pkrtz(float a, float b) {
  return __builtin_bit_cast(unsigned, __builtin_amdgcn_cvt_pkrtz(a, b));
}

// ---------------------------------------------------------------------------
// Kernel 1: projections
// grid (64, 12): x = 128-token tile, y = 128-outcol tile (0-3 q, 4-7 k, 8-11 v)
// ---------------------------------------------------------------------------
__global__ __launch_bounds__(256) void proj_kernel(
    const float* __restrict__ Xq, const float* __restrict__ Xk, const float* __restrict__ Xv,
    const float* __restrict__ Wq, const float* __restrict__ Wk, const float* __restrict__ Wv,
    const float* __restrict__ Bq, const float* __restrict__ Bk, const float* __restrict__ Bv,
    const unsigned char* __restrict__ mask,
    f16* __restrict__ Qf, f16* __restrict__ Kf, f16* __restrict__ VTf)
{
  __shared__ __align__(16) f16 As[128 * 32];
  __shared__ __align__(16) f16 Bs[128 * 32];
  __shared__ float biasS[128];

  const int tid = threadIdx.x;
  const int m0 = blockIdx.x * 128;
  const int n0 = blockIdx.y * 128;
  const int which = n0 >> 9;  // 0=q 1=k 2=v
  const float* X = (which == 0) ? Xq : (which == 1) ? Xk : Xv;
  const float* W = (which == 0) ? Wq : (which == 1) ? Wk : Wv;
  const float* Bi = (which == 0) ? Bq : (which == 1) ? Bk : Bv;
  const int nIn = n0 & 511;

  if (tid < 128) biasS[tid] = Bi[nIn + tid];

  const int w = tid >> 6, lane = tid & 63;
  const int l15 = lane & 15, g = lane >> 4;
  const int mh = w >> 1, nh = w & 1;

  f32x4 acc[4][4];
#pragma unroll
  for (int i = 0; i < 4; ++i)
#pragma unroll
    for (int j = 0; j < 4; ++j) acc[i][j] = (f32x4){0.f, 0.f, 0.f, 0.f};

  const int srow = tid >> 1;
  const int d0 = (tid & 1) * 16;

  for (int k0 = 0; k0 < 512; k0 += 32) {
    {
      const float4* xp4 = (const float4*)(X + (size_t)(m0 + srow) * 512 + k0 + d0);
      float4 x0 = xp4[0], x1 = xp4[1], x2 = xp4[2], x3 = xp4[3];
      f16x8 h0 = {(f16)x0.x, (f16)x0.y, (f16)x0.z, (f16)x0.w,
                  (f16)x1.x, (f16)x1.y, (f16)x1.z, (f16)x1.w};
      f16x8 h1 = {(f16)x2.x, (f16)x2.y, (f16)x2.z, (f16)x2.w,
                  (f16)x3.x, (f16)x3.y, (f16)x3.z, (f16)x3.w};
      const int base = srow * 32, sw = (srow & 3) << 3;
      *(uint4*)(As + base + ((d0 + 0) ^ sw)) = __builtin_bit_cast(uint4, h0);
      *(uint4*)(As + base + ((d0 + 8) ^ sw)) = __builtin_bit_cast(uint4, h1);
      const float4* wp4 = (const float4*)(W + (size_t)(nIn + srow) * 512 + k0 + d0);
      float4 w0 = wp4[0], w1 = wp4[1], w2 = wp4[2], w3 = wp4[3];
      f16x8 g0 = {(f16)w0.x, (f16)w0.y, (f16)w0.z, (f16)w0.w,
                  (f16)w1.x, (f16)w1.y, (f16)w1.z, (f16)w1.w};
      f16x8 g1 = {(f16)w2.x, (f16)w2.y, (f16)w2.z, (f16)w2.w,
                  (f16)w3.x, (f16)w3.y, (f16)w3.z, (f16)w3.w};
      *(uint4*)(Bs + base + ((d0 + 0) ^ sw)) = __builtin_bit_cast(uint4, g0);
      *(uint4*)(Bs + base + ((d0 + 8) ^ sw)) = __builtin_bit_cast(uint4, g1);
    }
    __syncthreads();
    f16x8 af[4], bf[4];
#pragma unroll
    for (int mt = 0; mt < 4; ++mt) {
      int row = mh * 64 + mt * 16 + l15;
      af[mt] = __builtin_bit_cast(f16x8, *(const uint4*)(As + row * 32 + ((8 * g) ^ ((row & 3) << 3))));
    }
#pragma unroll
    for (int nt = 0; nt < 4; ++nt) {
      int row = nh * 64 + nt * 16 + l15;
      bf[nt] = __builtin_bit_cast(f16x8, *(const uint4*)(Bs + row * 32 + ((8 * g) ^ ((row & 3) << 3))));
    }
#pragma unroll
    for (int mt = 0; mt < 4; ++mt)
#pragma unroll
      for (int nt = 0; nt < 4; ++nt)
        acc[mt][nt] = MFMA16(af[mt], bf[nt], acc[mt][nt]);
    __syncthreads();
  }

#pragma unroll
  for (int mt = 0; mt < 4; ++mt) {
#pragma unroll
    for (int r = 0; r < 4; ++r) {
      float val[4];
#pragma unroll
      for (int nt = 0; nt < 4; ++nt)
        val[nt] = acc[mt][nt][r] + biasS[nh * 64 + nt * 16 + l15];
      const int rowG = m0 + mh * 64 + mt * 16 + 4 * g + r;  // = b*2048 + tok
      if (which < 2) {
        float ss = 0.f;
#pragma unroll
        for (int nt = 0; nt < 4; ++nt) ss += val[nt] * val[nt];
#pragma unroll
        for (int off = 1; off < 16; off <<= 1) ss += __shfl_xor(ss, off);
        float inv = rsqrtf(fmaxf(ss, 1e-24f));
        if (which == 0) inv *= 0.125f;  // fold SCALE/ATTN_TEMP into q
        bool kill = (which == 1) && (mask[rowG] != 0);
#pragma unroll
        for (int nt = 0; nt < 4; ++nt) val[nt] = kill ? 0.f : val[nt] * inv;
      } else {
#pragma unroll
        for (int nt = 0; nt < 4; ++nt) {
          float x = fminf(fmaxf(val[nt], -15.f), 15.f);
          float t = exp2f(x * 2.88539008f);  // e^(2x)
          val[nt] = (t - 1.f) / (t + 1.f);   // tanh
        }
      }
      const int bb = rowG >> 11, tok = rowG & 2047;
#pragma unroll
      for (int nt = 0; nt < 4; ++nt) {
        const int cc = nIn + nh * 64 + nt * 16 + l15;
        const int hh = cc >> 6, ee = cc & 63;
        const size_t bhh = (size_t)bb * 8 + hh;
        if (which == 0) {
          // Q[bh][qt][qg][ec][lane][8]
          const int qt = tok >> 5, qg = (tok >> 4) & 1, lq = tok & 15;
          const int ec = ee >> 5, gq = (ee >> 3) & 3, sl = ee & 7;
          Qf[((((bhh * 64 + qt) * 2 + qg) * 2 + ec) * 64 + lq + (gq << 4)) * 8 + sl] = (f16)val[nt];
        } else if (which == 1) {
          // K[bh][kblk][ec][lane][8]
          const int kb = tok >> 4, lk = tok & 15;
          const int ec = ee >> 5, gk = (ee >> 3) & 3, sl = ee & 7;
          Kf[(((bhh * 128 + kb) * 2 + ec) * 64 + lk + (gk << 4)) * 8 + sl] = (f16)val[nt];
        } else {
          // V[bh][kblk][et][lane][4]
          const int kb = tok >> 4, gv = (tok >> 2) & 3, j = tok & 3;
          const int et = ee >> 4, lv = ee & 15;
          VTf[(((bhh * 128 + kb) * 4 + et) * 64 + lv + (gv << 4)) * 4 + j] = (f16)val[nt];
        }
      }
    }
  }
}

// ---------------------------------------------------------------------------
// Kernel 2: fused attention, TQ=32, 16 waves / 128 keys each.
// grid 2048 (XCD-chunked), block 1024.  All K/V/Q loads lane-contiguous.
// ---------------------------------------------------------------------------
__global__ __launch_bounds__(1024, 4) void attn_kernel(
    const f16* __restrict__ Qf, const f16* __restrict__ Kf,
    const f16* __restrict__ VTf, f16* __restrict__ ctx)
{
  __shared__ __align__(16) float cred[16][32][68];  // 139,264 B
  __shared__ unsigned cnt[6][16][32];               //  12,288 B
  __shared__ float mxA[16][32];                     //   2,048 B
  __shared__ float zzA[16][32];                     //   2,048 B

  const int tid = threadIdx.x;
  const int w = tid >> 6, lane = tid & 63;
  const int l15 = lane & 15, g = lane >> 4;

  const int bid = blockIdx.x;
  const int wg = (bid & 7) * 256 + (bid >> 3);   // XCD-chunked (2048 % 8 == 0)
  const int bh = wg >> 6;                        // 0..31 (4 bh per XCD)
  const int qt = wg & 63;
  const int q0 = qt * 32;
  const int b = bh >> 3, h = bh & 7;

  // Q fragments, coalesced: base + lane*8 halfs
  f16x8 aq[2][2];
#pragma unroll
  for (int qg = 0; qg < 2; ++qg)
#pragma unroll
    for (int ec = 0; ec < 2; ++ec)
      aq[qg][ec] = ldg8(Qf + ((((size_t)bh * 64 + qt) * 2 + qg) * 2 + ec) * 512 + lane * 8);

  // ---- P1: S^T into registers; K fragments shared by both q-groups --------
  // lane (g,l15): sp[qg*16+2s+p] packs S[key=128w+16s+4g+2p(+1)][q=q0+16qg+l15]
  uint32_t sp[32];
  float m0 = -1e30f, m1 = -1e30f;
#pragma unroll
  for (int s = 0; s < 8; ++s) {
    const f16* kpb = Kf + ((size_t)bh * 128 + w * 8 + s) * 1024 + lane * 8;
    f16x8 ak0 = ldg8(kpb);
    f16x8 ak1 = ldg8(kpb + 512);
    f32x4 a0 = {0.f, 0.f, 0.f, 0.f}, a1 = {0.f, 0.f, 0.f, 0.f};
    a0 = MFMA16(ak0, aq[0][0], a0);
    a0 = MFMA16(ak1, aq[0][1], a0);
    a1 = MFMA16(ak0, aq[1][0], a1);
    a1 = MFMA16(ak1, aq[1][1], a1);
    m0 = fmaxf(m0, fmaxf(fmaxf(a0[0], a0[1]), fmaxf(a0[2], a0[3])));
    m1 = fmaxf(m1, fmaxf(fmaxf(a1[0], a1[1]), fmaxf(a1[2], a1[3])));
    sp[2 * s]          = pkrtz(a0[0], a0[1]);
    sp[2 * s + 1]      = pkrtz(a0[2], a0[3]);
    sp[16 + 2 * s]     = pkrtz(a1[0], a1[1]);
    sp[16 + 2 * s + 1] = pkrtz(a1[2], a1[3]);
  }

  // ---- per-row max partials (reduce over g within wave, stash in LDS) -----
  m0 = fmaxf(m0, __shfl_xor(m0, 16)); m0 = fmaxf(m0, __shfl_xor(m0, 32));
  m1 = fmaxf(m1, __shfl_xor(m1, 16)); m1 = fmaxf(m1, __shfl_xor(m1, 32));
  if (lane < 16) { mxA[w][l15] = m0; mxA[w][16 + l15] = m1; }

  // ---- exact-ish top-205 threshold: 6 count passes, both rows per lane ----
  float tau0 = 0.0200f, lo0 = -0.30f, hi0 = 0.30f, bt0 = tau0;
  float tau1 = 0.0200f, lo1 = -0.30f, hi1 = 0.30f, bt1 = tau1;
  int bd0 = 1 << 30, bd1 = 1 << 30;
  for (int p = 0; p < 6; ++p) {
    const f16 th0 = (f16)tau0, th1 = (f16)tau1;
    f16x2 t20; t20.x = th0; t20.y = th0;
    f16x2 t21; t21.x = th1; t21.y = th1;
    unsigned cc0 = 0, cc1 = 0;
#pragma unroll
    for (int i = 0; i < 16; ++i) {
      f16x2 d = t20 - __builtin_bit_cast(f16x2, sp[i]);   // sign iff v > tau
      cc0 += (__builtin_bit_cast(unsigned, d) >> 15) & 0x10001u;
    }
#pragma unroll
    for (int i = 16; i < 32; ++i) {
      f16x2 d = t21 - __builtin_bit_cast(f16x2, sp[i]);
      cc1 += (__builtin_bit_cast(unsigned, d) >> 15) & 0x10001u;
    }
    int c0 = (int)((cc0 & 0xffffu) + (cc0 >> 16));
    int c1 = (int)((cc1 & 0xffffu) + (cc1 >> 16));
    c0 += __shfl_xor(c0, 16); c0 += __shfl_xor(c0, 32);
    c1 += __shfl_xor(c1, 16); c1 += __shfl_xor(c1, 32);
    if (lane < 16) cnt[p][w][l15] = (unsigned)c0 | ((unsigned)c1 << 16);
    __syncthreads();
    unsigned ct0 = 0, ct1 = 0;
#pragma unroll
    for (int i = 0; i < 16; ++i) {
      unsigned pk = cnt[p][i][l15];
      ct0 += pk & 0xffffu;
      ct1 += pk >> 16;
    }
    {
      int d = (int)ct0 - 205, ad = d < 0 ? -d : d;
      if (ad < bd0) { bd0 = ad; bt0 = tau0; }
      if ((int)ct0 >= 205) lo0 = tau0; else hi0 = tau0;
      float nt = tau0 + (float)d * (1.0f / 23000.0f);
      if (!(nt > lo0 && nt < hi0)) nt = 0.5f * (lo0 + hi0);
      tau0 = nt;
    }
    {
      int d = (int)ct1 - 205, ad = d < 0 ? -d : d;
      if (ad < bd1) { bd1 = ad; bt1 = tau1; }
      if ((int)ct1 >= 205) lo1 = tau1; else hi1 = tau1;
      float nt = tau1 + (float)d * (1.0f / 23000.0f);
      if (!(nt > lo1 && nt < hi1)) nt = 0.5f * (lo1 + hi1);
      tau1 = nt;
    }
  }
  const float tf0 = (float)((f16)bt0);  // same comparisons as count pass
  const float tf1 = (float)((f16)bt1);

  // ---- row max across waves, single exp pass (Z + masked-e in place) ------
  float mm0 = mxA[0][l15], mm1 = mxA[0][16 + l15];
#pragma unroll
  for (int i = 1; i < 16; ++i) {
    mm0 = fmaxf(mm0, mxA[i][l15]);
    mm1 = fmaxf(mm1, mxA[i][16 + l15]);
  }
  const float L2E = 1.44269504f;
  const float mL0 = mm0 * L2E, mL1 = mm1 * L2E;
  float z0 = 0.f, z1 = 0.f;
#pragma unroll
  for (int i = 0; i < 16; ++i) {
    f16x2 v2 = __builtin_bit_cast(f16x2, sp[i]);
    float v0 = (float)v2.x, v1 = (float)v2.y;
    float e0 = __builtin_amdgcn_exp2f(__builtin_fmaf(v0, L2E, -mL0));
    float e1 = __builtin_amdgcn_exp2f(__builtin_fmaf(v1, L2E, -mL0));
    z0 += e0 + e1;
    sp[i] = pkrtz((v0 > tf0) ? e0 : 0.f, (v1 > tf0) ? e1 : 0.f);
  }
#pragma unroll
  for (int i = 16; i < 32; ++i) {
    f16x2 v2 = __builtin_bit_cast(f16x2, sp[i]);
    float v0 = (float)v2.x, v1 = (float)v2.y;
    float e0 = __builtin_amdgcn_exp2f(__builtin_fmaf(v0, L2E, -mL1));
    float e1 = __builtin_amdgcn_exp2f(__builtin_fmaf(v1, L2E, -mL1));
    z1 += e0 + e1;
    sp[i] = pkrtz((v0 > tf1) ? e0 : 0.f, (v1 > tf1) ? e1 : 0.f);
  }
  z0 += __shfl_xor(z0, 16); z0 += __shfl_xor(z0, 32);
  z1 += __shfl_xor(z1, 16); z1 += __shfl_xor(z1, 32);
  if (lane < 16) { zzA[w][l15] = z0; zzA[w][16 + l15] = z1; }
  __syncthreads();
  float Z0 = 0.f, Z1 = 0.f;
#pragma unroll
  for (int i = 0; i < 16; ++i) { Z0 += zzA[i][l15]; Z1 += zzA[i][16 + l15]; }

  // ---- finalize weights: w = 0.99*e/Z + eps (selected), 0 otherwise -------
  const float s0 = 0.99f / Z0, s1 = 0.99f / Z1;
  const float epsw = 0.01f / 2048.0f;
#pragma unroll
  for (int i = 0; i < 16; ++i) {
    f16x2 e2 = __builtin_bit_cast(f16x2, sp[i]);
    float e0 = (float)e2.x, e1 = (float)e2.y;
    sp[i] = pkrtz((e0 != 0.f) ? __builtin_fmaf(e0, s0, epsw) : 0.f,
                  (e1 != 0.f) ? __builtin_fmaf(e1, s0, epsw) : 0.f);
  }
#pragma unroll
  for (int i = 16; i < 32; ++i) {
    f16x2 e2 = __builtin_bit_cast(f16x2, sp[i]);
    float e0 = (float)e2.x, e1 = (float)e2.y;
    sp[i] = pkrtz((e0 != 0.f) ? __builtin_fmaf(e0, s1, epsw) : 0.f,
                  (e1 != 0.f) ? __builtin_fmaf(e1, s1, epsw) : 0.f);
  }

  // ---- P3: partial ctx^T over this wave's 128 keys; V loads coalesced -----
#pragma unroll
  for (int et = 0; et < 4; ++et) {
    f32x4 a0 = {0.f, 0.f, 0.f, 0.f}, a1 = {0.f, 0.f, 0.f, 0.f};
#pragma unroll
    for (int s = 0; s < 8; ++s) {
      f16x4 av = ldg4(VTf + (((size_t)bh * 128 + w * 8 + s) * 4 + et) * 256 + lane * 4);
      uint2 p0; p0.x = sp[2 * s];      p0.y = sp[2 * s + 1];
      uint2 p1; p1.x = sp[16 + 2 * s]; p1.y = sp[16 + 2 * s + 1];
      a0 = MFMA16K16(av, __builtin_bit_cast(f16x4, p0), a0);
      a1 = MFMA16K16(av, __builtin_bit_cast(f16x4, p1), a1);
    }
    *(float4*)&cred[w][l15][et * 16 + 4 * g]      = __builtin_bit_cast(float4, a0);
    *(float4*)&cred[w][16 + l15][et * 16 + 4 * g] = __builtin_bit_cast(float4, a1);
  }
  __syncthreads();

  // ---- cross-wave reduce of ctx, store ------------------------------------
#pragma unroll
  for (int c = 0; c < 2; ++c) {
    const int cell = tid + c * 1024;      // 0..2047
    const int q = cell >> 6, e = cell & 63;
    float sum = 0.f;
#pragma unroll
    for (int j = 0; j < 16; ++j) sum += cred[j][q][e];
    ctx[((size_t)b * 2048 + q0 + q) * 512 + h * 64 + e] = (f16)sum;
  }
}

// ---------------------------------------------------------------------------
// Kernel 3: out = ctx @ Wo^T + bo.  grid (64, 4), block 256
// ---------------------------------------------------------------------------
__global__ __launch_bounds__(256) void out_kernel(
    const f16* __restrict__ CT, const float* __restrict__ Wo,
    const float* __restrict__ Bo, float* __restrict__ out)
{
  __shared__ __align__(16) f16 As[128 * 32];
  __shared__ __align__(16) f16 Bs[128 * 32];
  __shared__ float biasS[128];

  const int tid = threadIdx.x;
  const int m0 = blockIdx.x * 128;
  const int n0 = blockIdx.y * 128;
  if (tid < 128) biasS[tid] = Bo[n0 + tid];

  const int w = tid >> 6, lane = tid & 63;
  const int l15 = lane & 15, g = lane >> 4;
  const int mh = w >> 1, nh = w & 1;

  f32x4 acc[4][4];
#pragma unroll
  for (int i = 0; i < 4; ++i)
#pragma unroll
    for (int j = 0; j < 4; ++j) acc[i][j] = (f32x4){0.f, 0.f, 0.f, 0.f};

  const int srow = tid >> 1;
  const int d0 = (tid & 1) * 16;

  for (int k0 = 0; k0 < 512; k0 += 32) {
    {
      const uint4* ap = (const uint4*)(CT + (size_t)(m0 + srow) * 512 + k0 + d0);
      uint4 u0 = ap[0], u1 = ap[1];
      const int base = srow * 32, sw = (srow & 3) << 3;
      *(uint4*)(As + base + ((d0 + 0) ^ sw)) = u0;
      *(uint4*)(As + base + ((d0 + 8) ^ sw)) = u1;
      const float4* wp4 = (const float4*)(Wo + (size_t)(n0 + srow) * 512 + k0 + d0);
      float4 w0 = wp4[0], w1 = wp4[1], w2 = wp4[2], w3 = wp4[3];
      f16x8 g0 = {(f16)w0.x, (f16)w0.y, (f16)w0.z, (f16)w0.w,
                  (f16)w1.x, (f16)w1.y, (f16)w1.z, (f16)w1.w};
      f16x8 g1 = {(f16)w2.x, (f16)w2.y, (f16)w2.z, (f16)w2.w,
                  (f16)w3.x, (f16)w3.y, (f16)w3.z, (f16)w3.w};
      *(uint4*)(Bs + base + ((d0 + 0) ^ sw)) = __builtin_bit_cast(uint4, g0);
      *(uint4*)(Bs + base + ((d0 + 8) ^ sw)) = __builtin_bit_cast(uint4, g1);
    }
    __syncthreads();
    f16x8 af[4], bf[4];
#pragma unroll
    for (int mt = 0; mt < 4; ++mt) {
      int row = mh * 64 + mt * 16 + l15;
      af[mt] = __builtin_bit_cast(f16x8, *(const uint4*)(As + row * 32 + ((8 * g) ^ ((row & 3) << 3))));
    }
#pragma unroll
    for (int nt = 0; nt < 4; ++nt) {
      int row = nh * 64 + nt * 16 + l15;
      bf[nt] = __builtin_bit_cast(f16x8, *(const uint4*)(Bs + row * 32 + ((8 * g) ^ ((row & 3) << 3))));
    }
#pragma unroll
    for (int mt = 0; mt < 4; ++mt)
#pragma unroll
      for (int nt = 0; nt < 4; ++nt)
        acc[mt][nt] = MFMA16(af[mt], bf[nt], acc[mt][nt]);
    __syncthreads();
  }

#pragma unroll
  for (int mt = 0; mt < 4; ++mt) {
#pragma unroll
    for (int r = 0; r < 4; ++r) {
      const int rowG = m0 + mh * 64 + mt * 16 + 4 * g + r;
#pragma unroll
      for (int nt = 0; nt < 4; ++nt) {
        const int cc = nh * 64 + nt * 16 + l15;
        out[(size_t)rowG * 512 + n0 + cc] = acc[mt][nt][r] + biasS[cc];
      }
    }
  }
}

// ---------------------------------------------------------------------------
extern "C" void kernel_launch(void* const* d_in, const int* in_sizes, int n_in,
                              void* d_out, int out_size, void* d_ws, size_t ws_size,
                              hipStream_t stream)
{
  const float* q_in = (const float*)d_in[0];
  const float* k_in = (const float*)d_in[1];
  const float* v_in = (const float*)d_in[2];
  const float* Wq = (const float*)d_in[3];
  const float* bq = (const float*)d_in[4];
  const float* Wk = (const float*)d_in[5];
  const float* bk = (const float*)d_in[6];
  const float* Wv = (const float*)d_in[7];
  const float* bv = (const float*)d_in[8];
  const float* Wo = (const float*)d_in[9];
  const float* bo = (const float*)d_in[10];
  const unsigned char* mask = (const unsigned char*)d_in[11];

  // workspace: Q,K,VT,ctx fp16, 8 MB each = 32 MB total
  f16* Qf = (f16*)d_ws;
  f16* Kf = Qf + 4194304;
  f16* VTf = Kf + 4194304;
  f16* ctx = VTf + 4194304;

  proj_kernel<<<dim3(64, 12), 256, 0, stream>>>(q_in, k_in, v_in, Wq, Wk, Wv,
                                                bq, bk, bv, mask, Qf, Kf, VTf);
  attn_kernel<<<2048, 1024, 0, stream>>>(Qf, Kf, VTf, ctx);
  out_kernel<<<dim3(64, 4), 256, 0, stream>>>(ctx, Wo, bo, (float*)d_out);
}